// Round 2
// baseline (180.569 us; speedup 1.0000x reference)
//
#include <hip/hip_runtime.h>
#include <hip/hip_bf16.h>

// CapsuleLayer dynamic routing, MI355X.
// C=10, B=128, N=1152, IN=8, OUT=16, 3 routing iters.
// One block per (c,b) pair (1280 blocks), 384 threads; thread t owns route
// nodes n = t, t+384, t+768 with full prior rows P[n][0:16] in registers.
// Logits are scalar per (c,b,n) (reference's keepdims broadcast).
// Softmax with max-subtraction (bulletproof exp); s_o = sum e_n P[n,o] / sum e_n.
//
// DTYPE SELF-DETECTION: reference declares fp32 but harness evidence suggests a
// bf16 dataset conversion; round-1 NaN suggests fp32. Probe W's first 64 words
// as fp32: genuine fp32 N(0,1) -> ~all |v| in [1e-3,10]; bf16-packed data
// reinterpreted as fp32 has a near-random exponent field -> ~5% in range.
// Uniform branch selects load path + output dtype.

constexpr int C = 10, B = 128, N = 1152, IN = 8, OUT = 16;
constexpr int THREADS = 384;          // 6 waves
constexpr int NPT = 3;                // n rows per thread
constexpr int NWAVES = THREADS / 64;
constexpr int ROWPAD = 385;           // lds_part row stride
constexpr int SEGS = THREADS / OUT;   // 24
constexpr int SEGPAD = SEGS + 1;      // 25

__device__ __forceinline__ float bflo(unsigned int u) { return __uint_as_float(u << 16); }
__device__ __forceinline__ float bfhi(unsigned int u) { return __uint_as_float(u & 0xffff0000u); }

__global__ __launch_bounds__(THREADS)
void caps_route(const void* __restrict__ Xv, const void* __restrict__ Wv,
                void* __restrict__ Ov) {
    __shared__ float lds_part[OUT * ROWPAD];
    __shared__ float lds2[OUT * SEGPAD];
    __shared__ float lds_sum[NWAVES];
    __shared__ float lds_max[NWAVES];
    __shared__ float lds_out[OUT];

    const int t = threadIdx.x;
    const int blk = blockIdx.x;
    const int c = blk >> 7;    // consecutive blocks share c -> W[c] L2 reuse
    const int b = blk & 127;

    // ---- dtype probe (uniform across all threads/blocks) ----
    int cnt = 0;
    const float* probe = (const float*)Wv;
    #pragma unroll
    for (int k = 0; k < 64; ++k) {
        const float v = __builtin_fabsf(probe[k]);
        cnt += (v > 1e-3f && v < 10.f) ? 1 : 0;
    }
    const bool is_f32 = (cnt >= 32);

    float p[NPT][OUT];

    // ---- priors: P[n][o] = sum_i x[b,n,i] * W[c,n,i,o], fp32 accumulate ----
    if (is_f32) {
        const float* Xf = (const float*)Xv;
        const float* Wf = (const float*)Wv;
        #pragma unroll
        for (int j = 0; j < NPT; ++j) {
            const int n = t + j * THREADS;
            const float4* xr = (const float4*)(Xf + (size_t)(b * N + n) * IN);
            float4 xa = xr[0], xb = xr[1];
            const float xf[8] = { xa.x, xa.y, xa.z, xa.w, xb.x, xb.y, xb.z, xb.w };
            const float4* wr = (const float4*)(Wf + (size_t)(c * N + n) * (IN * OUT));
            #pragma unroll
            for (int o = 0; o < OUT; ++o) p[j][o] = 0.f;
            #pragma unroll
            for (int i = 0; i < IN; ++i) {
                const float xi = xf[i];
                #pragma unroll
                for (int q = 0; q < 4; ++q) {
                    const float4 w = wr[i * 4 + q];
                    p[j][q * 4 + 0] = fmaf(xi, w.x, p[j][q * 4 + 0]);
                    p[j][q * 4 + 1] = fmaf(xi, w.y, p[j][q * 4 + 1]);
                    p[j][q * 4 + 2] = fmaf(xi, w.z, p[j][q * 4 + 2]);
                    p[j][q * 4 + 3] = fmaf(xi, w.w, p[j][q * 4 + 3]);
                }
            }
        }
    } else {
        const ushort* Xp = (const ushort*)Xv;
        const ushort* Wp = (const ushort*)Wv;
        #pragma unroll
        for (int j = 0; j < NPT; ++j) {
            const int n = t + j * THREADS;
            const uint4 xq = *(const uint4*)(Xp + (size_t)(b * N + n) * IN);
            const float xf[8] = { bflo(xq.x), bfhi(xq.x), bflo(xq.y), bfhi(xq.y),
                                  bflo(xq.z), bfhi(xq.z), bflo(xq.w), bfhi(xq.w) };
            const uint4* wr = (const uint4*)(Wp + (size_t)(c * N + n) * (IN * OUT));
            #pragma unroll
            for (int o = 0; o < OUT; ++o) p[j][o] = 0.f;
            #pragma unroll
            for (int i = 0; i < IN; ++i) {
                const uint4 w0 = wr[2 * i];
                const uint4 w1 = wr[2 * i + 1];
                const float xi = xf[i];
                p[j][0]  = fmaf(xi, bflo(w0.x), p[j][0]);
                p[j][1]  = fmaf(xi, bfhi(w0.x), p[j][1]);
                p[j][2]  = fmaf(xi, bflo(w0.y), p[j][2]);
                p[j][3]  = fmaf(xi, bfhi(w0.y), p[j][3]);
                p[j][4]  = fmaf(xi, bflo(w0.z), p[j][4]);
                p[j][5]  = fmaf(xi, bfhi(w0.z), p[j][5]);
                p[j][6]  = fmaf(xi, bflo(w0.w), p[j][6]);
                p[j][7]  = fmaf(xi, bfhi(w0.w), p[j][7]);
                p[j][8]  = fmaf(xi, bflo(w1.x), p[j][8]);
                p[j][9]  = fmaf(xi, bfhi(w1.x), p[j][9]);
                p[j][10] = fmaf(xi, bflo(w1.y), p[j][10]);
                p[j][11] = fmaf(xi, bfhi(w1.y), p[j][11]);
                p[j][12] = fmaf(xi, bflo(w1.z), p[j][12]);
                p[j][13] = fmaf(xi, bfhi(w1.z), p[j][13]);
                p[j][14] = fmaf(xi, bflo(w1.w), p[j][14]);
                p[j][15] = fmaf(xi, bfhi(w1.w), p[j][15]);
            }
        }
    }

    // ---- dynamic routing ----
    float logit[NPT] = {0.f, 0.f, 0.f};
    const int wid = t >> 6;
    const int lane = t & 63;

    for (int it = 0; it < 3; ++it) {
        // block-wide max of logits (softmax shift)
        float m = fmaxf(logit[0], fmaxf(logit[1], logit[2]));
        #pragma unroll
        for (int d = 1; d < 64; d <<= 1) m = fmaxf(m, __shfl_xor(m, d, 64));
        if (lane == 0) lds_max[wid] = m;
        __syncthreads();   // D
        float mm = lds_max[0];
        #pragma unroll
        for (int w = 1; w < NWAVES; ++w) mm = fmaxf(mm, lds_max[w]);

        const float e0 = __expf(logit[0] - mm);
        const float e1 = __expf(logit[1] - mm);
        const float e2 = __expf(logit[2] - mm);

        // weighted partials into LDS columns (lanes consecutive -> conflict-free)
        #pragma unroll
        for (int o = 0; o < OUT; ++o) {
            float sp = e0 * p[0][o];
            sp = fmaf(e1, p[1][o], sp);
            sp = fmaf(e2, p[2][o], sp);
            lds_part[o * ROWPAD + t] = sp;
        }
        // softmax denominator: wave butterfly + per-wave slot
        float ss = e0 + e1 + e2;
        #pragma unroll
        for (int d = 1; d < 64; d <<= 1) ss += __shfl_xor(ss, d, 64);
        if (lane == 0) lds_sum[wid] = ss;
        __syncthreads();   // A

        // tree stage 1: 384 columns -> 24 segments per o
        const int oo = t & 15, seg = t >> 4;
        float p2 = 0.f;
        #pragma unroll
        for (int k = 0; k < 16; ++k) p2 += lds_part[oo * ROWPAD + seg * 16 + k];
        lds2[oo * SEGPAD + seg] = p2;
        __syncthreads();   // B

        // tree stage 2 + squash on lanes 0..15 of wave 0
        if (t < OUT) {
            float so = 0.f;
            #pragma unroll
            for (int s2 = 0; s2 < SEGS; ++s2) so += lds2[t * SEGPAD + s2];
            float S = 0.f;
            #pragma unroll
            for (int w = 0; w < NWAVES; ++w) S += lds_sum[w];
            so /= S;                               // s_o = sum_n attn_n * P[n,o]
            float r = so * so;                     // sq_norm via 16-lane butterfly
            r += __shfl_xor(r, 1, 64);
            r += __shfl_xor(r, 2, 64);
            r += __shfl_xor(r, 4, 64);
            r += __shfl_xor(r, 8, 64);
            const float ov = so * (r / ((1.f + r) * sqrtf(r + 1e-8f)));
            if (it == 2) {
                if (is_f32) {
                    ((float*)Ov)[blk * OUT + t] = ov;
                } else {
                    __hip_bfloat16 h = __float2bfloat16(ov);
                    ((ushort*)Ov)[blk * OUT + t] = *(const ushort*)&h;
                }
            } else {
                lds_out[t] = ov;
            }
        }

        if (it < 2) {
            __syncthreads();   // C
            float ov_[OUT];
            #pragma unroll
            for (int o = 0; o < OUT; ++o) ov_[o] = lds_out[o];
            // logit update is thread-local: delta[n] = dot(out, P[n,:])
            #pragma unroll
            for (int j = 0; j < NPT; ++j) {
                float d = 0.f;
                #pragma unroll
                for (int o = 0; o < OUT; ++o) d = fmaf(ov_[o], p[j][o], d);
                logit[j] += d;
            }
        }
    }
}

extern "C" void kernel_launch(void* const* d_in, const int* in_sizes, int n_in,
                              void* d_out, int out_size, void* d_ws, size_t ws_size,
                              hipStream_t stream) {
    hipLaunchKernelGGL(caps_route, dim3(C * B), dim3(THREADS), 0, stream,
                       d_in[0], d_in[1], d_out);
}

// Round 3
// 179.327 us; speedup vs baseline: 1.0069x; 1.0069x over previous
//
#include <hip/hip_runtime.h>

// CapsuleLayer dynamic routing, MI355X. fp32 in/out (verified round 2:
// absmax 2.4e-4 << bf16 ULP -> fp32 branch ran; probe removed).
// C=10, B=128, N=1152, IN=8, OUT=16, 3 routing iters.
//
// Layout v2 — coalesced W loads + batch pairing:
//   One block per (c, b-pair): 640 blocks, 384 threads (6 waves).
//   Lane l of a wave: o-quad q = l&3 (owns o = q*4..q*4+3), row-sub r = l>>2.
//   Wave w handles rows [w*192, (w+1)*192) in 12 passes of 16 rows.
//   W load per (pass,i): lane reads float4 at ((c*N+n)*8+i)*16 + q*4 floats
//   -> one instr covers 16 rows x 64B fully-consumed cache lines (coalesced;
//   the old layout hit 64 lines/instr = TA-bound at 137us).
//   W registers serve BOTH batches of the pair (halves W L2 traffic).
//   Per-thread state: P[2][12][4] = 96 fp32 priors + logit[2][12].
// Routing: logits are scalar per (c,b,n) (reference keepdims broadcast).
//   Unnormalized softmax (|logit| <~ 25, exp safe in fp32).
//   Row-dot across the quad via __shfl_xor 1,2; wave reduction via
//   __shfl_xor 4..32; cross-wave via ~1KB LDS. 2 barriers/iter.

constexpr int C = 10, B = 128, N = 1152, IN = 8, OUT = 16;
constexpr int THREADS = 384;
constexpr int NW = THREADS / 64;          // 6 waves
constexpr int G = 2;                      // batches per block
constexpr int PASSES = N / (NW * 16);     // 12

__global__ __launch_bounds__(THREADS, 3)
void caps_route(const float* __restrict__ Xf, const float* __restrict__ Wf,
                float* __restrict__ Of) {
    __shared__ float lds_s[G][NW][OUT];   // per-wave weighted sums
    __shared__ float lds_sum[G][NW];      // per-wave softmax denominators
    __shared__ float lds_out[G][OUT];     // squashed outputs

    const int t = threadIdx.x;
    const int l = t & 63;
    const int wid = t >> 6;
    const int q = l & 3;        // o-quad: owns o = q*4 .. q*4+3
    const int rsub = l >> 2;    // row-sub within a pass (0..15)
    const int blk = blockIdx.x;
    const int c = blk >> 6;     // 64 consecutive blocks share c -> W[c] in L2
    const int b0 = (blk & 63) * G;

    float P[G][PASSES][4];

    // ---- priors: P[n][o] = sum_i x[b,n,i] * W[c,n,i,o] ----
    #pragma unroll
    for (int p = 0; p < PASSES; ++p) {
        const int n = wid * (16 * PASSES) + p * 16 + rsub;
        const float4* wr = (const float4*)(Wf + (size_t)(c * N + n) * (IN * OUT));
        float4 wv[IN];
        #pragma unroll
        for (int i = 0; i < IN; ++i) wv[i] = wr[i * 4 + q];   // coalesced: 16 full lines
        #pragma unroll
        for (int g = 0; g < G; ++g) {
            const float* xb = Xf + ((size_t)((b0 + g) * N + n)) * IN;
            const float4 xa = ((const float4*)xb)[0];
            const float4 xc = ((const float4*)xb)[1];
            const float xs[8] = { xa.x, xa.y, xa.z, xa.w, xc.x, xc.y, xc.z, xc.w };
            float a0 = 0.f, a1 = 0.f, a2 = 0.f, a3 = 0.f;
            #pragma unroll
            for (int i = 0; i < IN; ++i) {
                a0 = fmaf(xs[i], wv[i].x, a0);
                a1 = fmaf(xs[i], wv[i].y, a1);
                a2 = fmaf(xs[i], wv[i].z, a2);
                a3 = fmaf(xs[i], wv[i].w, a3);
            }
            P[g][p][0] = a0; P[g][p][1] = a1; P[g][p][2] = a2; P[g][p][3] = a3;
        }
    }

    // ---- dynamic routing ----
    float logit[G][PASSES];
    #pragma unroll
    for (int g = 0; g < G; ++g)
        #pragma unroll
        for (int p = 0; p < PASSES; ++p) logit[g][p] = 0.f;

    for (int it = 0; it < 3; ++it) {
        float s4[G][4] = {{0.f,0.f,0.f,0.f},{0.f,0.f,0.f,0.f}};
        float ssum[G] = {0.f, 0.f};
        #pragma unroll
        for (int g = 0; g < G; ++g) {
            #pragma unroll
            for (int p = 0; p < PASSES; ++p) {
                const float e = __expf(logit[g][p]);   // replicated across quad
                ssum[g] += e;
                #pragma unroll
                for (int k = 0; k < 4; ++k) s4[g][k] = fmaf(e, P[g][p][k], s4[g][k]);
            }
        }
        // reduce across the 16 row-subs of the wave (masks 4..32; quad bits
        // 0,1 are replicas for ssum / distinct-o for s4 -> not summed)
        #pragma unroll
        for (int m = 4; m < 64; m <<= 1) {
            #pragma unroll
            for (int g = 0; g < G; ++g) {
                ssum[g] += __shfl_xor(ssum[g], m, 64);
                #pragma unroll
                for (int k = 0; k < 4; ++k) s4[g][k] += __shfl_xor(s4[g][k], m, 64);
            }
        }
        if (l < 4) {  // lane l == quad q: owns o = l*4..l*4+3
            #pragma unroll
            for (int g = 0; g < G; ++g)
                #pragma unroll
                for (int k = 0; k < 4; ++k) lds_s[g][wid][l * 4 + k] = s4[g][k];
        }
        if (l == 0) { lds_sum[0][wid] = ssum[0]; lds_sum[1][wid] = ssum[1]; }
        __syncthreads();   // A

        // cross-wave combine + squash on t<32 (wave 0; 16-lane groups per g)
        if (t < 32) {
            const int g = t >> 4, o = t & 15;
            float so = 0.f, S = 0.f;
            #pragma unroll
            for (int w = 0; w < NW; ++w) { so += lds_s[g][w][o]; S += lds_sum[g][w]; }
            so /= S;                          // s_o = softmax-weighted prior sum
            float r = so * so;                // ||s||^2 via 16-lane butterfly
            r += __shfl_xor(r, 1, 64);
            r += __shfl_xor(r, 2, 64);
            r += __shfl_xor(r, 4, 64);
            r += __shfl_xor(r, 8, 64);
            const float ov = so * (r / ((1.f + r) * sqrtf(r + 1e-8f)));
            if (it == 2) Of[((size_t)c * B + b0 + g) * OUT + o] = ov;
            else         lds_out[g][o] = ov;
        }

        if (it < 2) {
            __syncthreads();   // B
            float o4[G][4];
            #pragma unroll
            for (int g = 0; g < G; ++g)
                #pragma unroll
                for (int k = 0; k < 4; ++k) o4[g][k] = lds_out[g][q * 4 + k];
            // logit update: delta[n] = dot(out, P[n,:]) -> quad butterfly
            #pragma unroll
            for (int g = 0; g < G; ++g) {
                #pragma unroll
                for (int p = 0; p < PASSES; ++p) {
                    float d = o4[g][0] * P[g][p][0];
                    d = fmaf(o4[g][1], P[g][p][1], d);
                    d = fmaf(o4[g][2], P[g][p][2], d);
                    d = fmaf(o4[g][3], P[g][p][3], d);
                    d += __shfl_xor(d, 1, 64);
                    d += __shfl_xor(d, 2, 64);
                    logit[g][p] += d;
                }
            }
        }
    }
}

extern "C" void kernel_launch(void* const* d_in, const int* in_sizes, int n_in,
                              void* d_out, int out_size, void* d_ws, size_t ws_size,
                              hipStream_t stream) {
    const float* X = (const float*)d_in[0];   // [B,N,IN] fp32
    const float* W = (const float*)d_in[1];   // [C,N,IN,OUT] fp32
    float* O = (float*)d_out;                 // [C,B,OUT] fp32
    hipLaunchKernelGGL(caps_route, dim3(C * (B / G)), dim3(THREADS), 0, stream, X, W, O);
}

// Round 4
// 110.644 us; speedup vs baseline: 1.6320x; 1.6208x over previous
//
#include <hip/hip_runtime.h>

// CapsuleLayer dynamic routing, MI355X. fp32 in/out.
// C=10, B=128, N=1152, IN=8, OUT=16, 3 routing iters.
//
// Layout v2 (round 3) + spill fix (round 4):
//   Round 3's __launch_bounds__(384,3) made the allocator budget 84 VGPRs
//   (512/6) -> the 96-float P array spilled to scratch: WRITE_SIZE showed
//   94 MB of spill stores (= 96 fp32 x 245,760 threads), re-read from HBM
//   each routing iter -> 128 us at VALUBusy 8.5%. Fix: no occupancy hint;
//   ~150-170 VGPRs keeps P in registers, natural occupancy 3 waves/SIMD.
//
//   One block per (c, b-pair): 640 blocks, 384 threads (6 waves).
//   Lane l: o-quad q = l&3 (owns o = q*4..q*4+3), row-sub r = l>>2.
//   Wave w handles rows [w*192, (w+1)*192) in 12 passes of 16 rows.
//   W float4 load covers 16 rows x 64 B fully-consumed lines (16 lines/instr,
//   the intrinsic minimum). W registers serve both batches (halves L2 traffic).
//   Per-thread state: P[2][12][4] = 96 fp32 + logit[2][12].
// Routing: logits scalar per (c,b,n) (reference keepdims broadcast).
//   Unnormalized softmax (|logit| <~ 25, exp safe in fp32).
//   Quad dot via __shfl_xor 1,2; wave reduce via 4..32; cross-wave via 1KB LDS.

constexpr int C = 10, B = 128, N = 1152, IN = 8, OUT = 16;
constexpr int THREADS = 384;
constexpr int NW = THREADS / 64;          // 6 waves
constexpr int G = 2;                      // batches per block
constexpr int PASSES = N / (NW * 16);     // 12

__global__ __launch_bounds__(THREADS)
void caps_route(const float* __restrict__ Xf, const float* __restrict__ Wf,
                float* __restrict__ Of) {
    __shared__ float lds_s[G][NW][OUT];   // per-wave weighted sums
    __shared__ float lds_sum[G][NW];      // per-wave softmax denominators
    __shared__ float lds_out[G][OUT];     // squashed outputs

    const int t = threadIdx.x;
    const int l = t & 63;
    const int wid = t >> 6;
    const int q = l & 3;        // o-quad: owns o = q*4 .. q*4+3
    const int rsub = l >> 2;    // row-sub within a pass (0..15)
    const int blk = blockIdx.x;
    const int c = blk >> 6;     // 64 consecutive blocks share c -> W[c] in L2
    const int b0 = (blk & 63) * G;

    float P[G][PASSES][4];

    // ---- priors: P[n][o] = sum_i x[b,n,i] * W[c,n,i,o] ----
    #pragma unroll
    for (int p = 0; p < PASSES; ++p) {
        const int n = wid * (16 * PASSES) + p * 16 + rsub;
        const float4* wr = (const float4*)(Wf + (size_t)(c * N + n) * (IN * OUT));
        float4 wv[IN];
        #pragma unroll
        for (int i = 0; i < IN; ++i) wv[i] = wr[i * 4 + q];   // 16 full lines/instr
        #pragma unroll
        for (int g = 0; g < G; ++g) {
            const float* xb = Xf + ((size_t)((b0 + g) * N + n)) * IN;
            const float4 xa = ((const float4*)xb)[0];
            const float4 xc = ((const float4*)xb)[1];
            const float xs[8] = { xa.x, xa.y, xa.z, xa.w, xc.x, xc.y, xc.z, xc.w };
            float a0 = 0.f, a1 = 0.f, a2 = 0.f, a3 = 0.f;
            #pragma unroll
            for (int i = 0; i < IN; ++i) {
                a0 = fmaf(xs[i], wv[i].x, a0);
                a1 = fmaf(xs[i], wv[i].y, a1);
                a2 = fmaf(xs[i], wv[i].z, a2);
                a3 = fmaf(xs[i], wv[i].w, a3);
            }
            P[g][p][0] = a0; P[g][p][1] = a1; P[g][p][2] = a2; P[g][p][3] = a3;
        }
    }

    // ---- dynamic routing ----
    float logit[G][PASSES];
    #pragma unroll
    for (int g = 0; g < G; ++g)
        #pragma unroll
        for (int p = 0; p < PASSES; ++p) logit[g][p] = 0.f;

    for (int it = 0; it < 3; ++it) {
        float s4[G][4];
        float ssum[G];
        #pragma unroll
        for (int g = 0; g < G; ++g) {
            ssum[g] = 0.f;
            #pragma unroll
            for (int k = 0; k < 4; ++k) s4[g][k] = 0.f;
        }
        #pragma unroll
        for (int g = 0; g < G; ++g) {
            #pragma unroll
            for (int p = 0; p < PASSES; ++p) {
                const float e = __expf(logit[g][p]);   // replicated across quad
                ssum[g] += e;
                #pragma unroll
                for (int k = 0; k < 4; ++k) s4[g][k] = fmaf(e, P[g][p][k], s4[g][k]);
            }
        }
        // reduce across the 16 row-subs of the wave (masks 4..32; quad bits
        // 0,1 are replicas for ssum / distinct-o for s4 -> not summed)
        #pragma unroll
        for (int m = 4; m < 64; m <<= 1) {
            #pragma unroll
            for (int g = 0; g < G; ++g) {
                ssum[g] += __shfl_xor(ssum[g], m, 64);
                #pragma unroll
                for (int k = 0; k < 4; ++k) s4[g][k] += __shfl_xor(s4[g][k], m, 64);
            }
        }
        if (l < 4) {  // lane l == quad q: owns o = l*4..l*4+3
            #pragma unroll
            for (int g = 0; g < G; ++g)
                #pragma unroll
                for (int k = 0; k < 4; ++k) lds_s[g][wid][l * 4 + k] = s4[g][k];
        }
        if (l == 0) {
            #pragma unroll
            for (int g = 0; g < G; ++g) lds_sum[g][wid] = ssum[g];
        }
        __syncthreads();   // A

        // cross-wave combine + squash on t<32 (wave 0; 16-lane groups per g)
        if (t < 32) {
            const int g = t >> 4, o = t & 15;
            float so = 0.f, S = 0.f;
            #pragma unroll
            for (int w = 0; w < NW; ++w) { so += lds_s[g][w][o]; S += lds_sum[g][w]; }
            so /= S;                          // s_o = softmax-weighted prior sum
            float r = so * so;                // ||s||^2 via 16-lane butterfly
            r += __shfl_xor(r, 1, 64);
            r += __shfl_xor(r, 2, 64);
            r += __shfl_xor(r, 4, 64);
            r += __shfl_xor(r, 8, 64);
            const float ov = so * (r / ((1.f + r) * sqrtf(r + 1e-8f)));
            if (it == 2) Of[((size_t)c * B + b0 + g) * OUT + o] = ov;
            else         lds_out[g][o] = ov;
        }

        if (it < 2) {
            __syncthreads();   // B
            float o4[G][4];
            #pragma unroll
            for (int g = 0; g < G; ++g)
                #pragma unroll
                for (int k = 0; k < 4; ++k) o4[g][k] = lds_out[g][q * 4 + k];
            // logit update: delta[n] = dot(out, P[n,:]) -> quad butterfly
            #pragma unroll
            for (int g = 0; g < G; ++g) {
                #pragma unroll
                for (int p = 0; p < PASSES; ++p) {
                    float d = o4[g][0] * P[g][p][0];
                    d = fmaf(o4[g][1], P[g][p][1], d);
                    d = fmaf(o4[g][2], P[g][p][2], d);
                    d = fmaf(o4[g][3], P[g][p][3], d);
                    d += __shfl_xor(d, 1, 64);
                    d += __shfl_xor(d, 2, 64);
                    logit[g][p] += d;
                }
            }
        }
    }
}

extern "C" void kernel_launch(void* const* d_in, const int* in_sizes, int n_in,
                              void* d_out, int out_size, void* d_ws, size_t ws_size,
                              hipStream_t stream) {
    const float* X = (const float*)d_in[0];   // [B,N,IN] fp32
    const float* W = (const float*)d_in[1];   // [C,N,IN,OUT] fp32
    float* O = (float*)d_out;                 // [C,B,OUT] fp32
    hipLaunchKernelGGL(caps_route, dim3(C * (B / G)), dim3(THREADS), 0, stream, X, W, O);
}

// Round 5
// 100.851 us; speedup vs baseline: 1.7904x; 1.0971x over previous
//
#include <hip/hip_runtime.h>

// CapsuleLayer dynamic routing, MI355X. fp32 in/out.
// C=10, B=128, N=1152, IN=8, OUT=16, 3 routing iters.
//
// v3 (round 5): G=1 — one block per (c,b), 1280 blocks, 384 threads (6 waves).
//   Round-4 G=2 held 96 P-floats/thread -> allocator landed at exactly 128
//   VGPR (4 waves/SIMD) with ~5 MB residual scratch spill re-read from HBM in
//   the routing loop, and 640 blocks packed 2/CU -> 12 waves/CU with a fat
//   tail. G=1 halves per-thread state (48 P + 12 logit): target ~100 VGPR ->
//   5 waves/SIMD -> 3 blocks/CU (18 waves/CU), no spill, finer grid packing.
//   W is logically read twice as often but stays L2-resident.
//
// Layout: lane l of a wave: o-quad q = l&3 (owns o = q*4..q*4+3),
//   row-sub r = l>>2. Wave w covers rows [w*192,(w+1)*192) in 12 passes of 16.
//   W float4 load: 16 rows x 64 B fully-consumed lines per instr (coalesced
//   minimum; the round-2 row-per-lane layout hit 64 lines/instr = 137 us).
// Routing: logits scalar per (c,b,n) (reference keepdims broadcast makes the
//   logit constant along OUT). Unnormalized softmax (|logit| <~ 30, fp32-safe).
//   Quad dot via __shfl_xor 1,2; wave reduce 4..32; cross-wave via ~0.5KB LDS.

constexpr int C = 10, B = 128, N = 1152, IN = 8, OUT = 16;
constexpr int THREADS = 384;
constexpr int NW = THREADS / 64;          // 6 waves
constexpr int PASSES = N / (NW * 16);     // 12

__global__ __launch_bounds__(THREADS)
void caps_route(const float* __restrict__ Xf, const float* __restrict__ Wf,
                float* __restrict__ Of) {
    __shared__ float lds_s[NW][OUT];      // per-wave weighted sums
    __shared__ float lds_sum[NW];         // per-wave softmax denominators
    __shared__ float lds_out[OUT];        // squashed output

    const int t = threadIdx.x;
    const int l = t & 63;
    const int wid = t >> 6;
    const int q = l & 3;        // o-quad: owns o = q*4 .. q*4+3
    const int rsub = l >> 2;    // row-sub within a pass (0..15)
    const int blk = blockIdx.x;
    const int c = blk >> 7;     // 128 consecutive blocks share c -> W[c] in L2
    const int b = blk & 127;

    float P[PASSES][4];
    float logit[PASSES];

    // ---- priors: P[n][o] = sum_i x[b,n,i] * W[c,n,i,o] ----
    #pragma unroll
    for (int p = 0; p < PASSES; ++p) {
        const int n = wid * (16 * PASSES) + p * 16 + rsub;
        const float4* wr = (const float4*)(Wf + (size_t)(c * N + n) * (IN * OUT));
        const float4* xr = (const float4*)(Xf + (size_t)(b * N + n) * IN);
        const float4 xa = xr[0], xb = xr[1];
        const float xs[8] = { xa.x, xa.y, xa.z, xa.w, xb.x, xb.y, xb.z, xb.w };
        float a0 = 0.f, a1 = 0.f, a2 = 0.f, a3 = 0.f;
        #pragma unroll
        for (int i = 0; i < IN; ++i) {
            const float4 w = wr[i * 4 + q];   // 16 full 64B lines per wave-instr
            a0 = fmaf(xs[i], w.x, a0);
            a1 = fmaf(xs[i], w.y, a1);
            a2 = fmaf(xs[i], w.z, a2);
            a3 = fmaf(xs[i], w.w, a3);
        }
        P[p][0] = a0; P[p][1] = a1; P[p][2] = a2; P[p][3] = a3;
        logit[p] = 0.f;
    }

    // ---- dynamic routing ----
    for (int it = 0; it < 3; ++it) {
        float s0 = 0.f, s1 = 0.f, s2 = 0.f, s3 = 0.f, ssum = 0.f;
        #pragma unroll
        for (int p = 0; p < PASSES; ++p) {
            const float e = __expf(logit[p]);   // replicated across the quad
            ssum += e;
            s0 = fmaf(e, P[p][0], s0);
            s1 = fmaf(e, P[p][1], s1);
            s2 = fmaf(e, P[p][2], s2);
            s3 = fmaf(e, P[p][3], s3);
        }
        // reduce across the 16 row-subs of the wave (masks 4..32; quad bits
        // 0,1 carry replicas (ssum) / distinct o (s0..s3) -> not summed)
        #pragma unroll
        for (int m = 4; m < 64; m <<= 1) {
            ssum += __shfl_xor(ssum, m, 64);
            s0 += __shfl_xor(s0, m, 64);
            s1 += __shfl_xor(s1, m, 64);
            s2 += __shfl_xor(s2, m, 64);
            s3 += __shfl_xor(s3, m, 64);
        }
        if (l < 4) {            // lane l == quad q: owns o = l*4..l*4+3
            lds_s[wid][l * 4 + 0] = s0;
            lds_s[wid][l * 4 + 1] = s1;
            lds_s[wid][l * 4 + 2] = s2;
            lds_s[wid][l * 4 + 3] = s3;
        }
        if (l == 0) lds_sum[wid] = ssum;
        __syncthreads();   // A

        // cross-wave combine + squash on t<16 (wave 0)
        if (t < OUT) {
            float so = 0.f, S = 0.f;
            #pragma unroll
            for (int w = 0; w < NW; ++w) { so += lds_s[w][t]; S += lds_sum[w]; }
            so /= S;                          // s_o = softmax-weighted prior sum
            float r = so * so;                // ||s||^2 via 16-lane butterfly
            r += __shfl_xor(r, 1, 64);
            r += __shfl_xor(r, 2, 64);
            r += __shfl_xor(r, 4, 64);
            r += __shfl_xor(r, 8, 64);
            const float ov = so * (r / ((1.f + r) * sqrtf(r + 1e-8f)));
            if (it == 2) Of[((size_t)c * B + b) * OUT + t] = ov;
            else         lds_out[t] = ov;
        }

        if (it < 2) {
            __syncthreads();   // B
            const float o0 = lds_out[q * 4 + 0];
            const float o1 = lds_out[q * 4 + 1];
            const float o2 = lds_out[q * 4 + 2];
            const float o3 = lds_out[q * 4 + 3];
            // logit update: delta[n] = dot(out, P[n,:]) -> quad butterfly
            #pragma unroll
            for (int p = 0; p < PASSES; ++p) {
                float d = o0 * P[p][0];
                d = fmaf(o1, P[p][1], d);
                d = fmaf(o2, P[p][2], d);
                d = fmaf(o3, P[p][3], d);
                d += __shfl_xor(d, 1, 64);
                d += __shfl_xor(d, 2, 64);
                logit[p] += d;
            }
        }
    }
}

extern "C" void kernel_launch(void* const* d_in, const int* in_sizes, int n_in,
                              void* d_out, int out_size, void* d_ws, size_t ws_size,
                              hipStream_t stream) {
    const float* X = (const float*)d_in[0];   // [B,N,IN] fp32
    const float* W = (const float*)d_in[1];   // [C,N,IN,OUT] fp32
    float* O = (float*)d_out;                 // [C,B,OUT] fp32
    hipLaunchKernelGGL(caps_route, dim3(C * B), dim3(THREADS), 0, stream, X, W, O);
}